// Round 1
// baseline (769.480 us; speedup 1.0000x reference)
//
#include <hip/hip_runtime.h>

#define NN 32      // nodes
#define FF 64      // GAT out features
#define HH 128     // LSTM hidden
#define G4 512     // 4*H
#define BB 32      // batch
#define TT 512     // time steps
#define ET 128     // 96 edges + 32 self loops
#define NPOS (BB*TT)

__device__ __forceinline__ float frcp(float x) { return __builtin_amdgcn_rcpf(x); }
__device__ __forceinline__ float sigm(float x) { return frcp(1.f + __expf(-x)); }
__device__ __forceinline__ float tanh_fast(float x) { return 1.f - 2.f * frcp(1.f + __expf(2.f * x)); }

// ---------------- prep: fold GAT linear into LSTM input weights ----------------
// W_eff[n,j] = sum_f w_gat[f] * W_ih[n*FF+f, j]
// bias_eff[j] = b_ih[j] + b_hh[j] + sum_{n,f} b_gat[f] * W_ih[n*FF+f, j]
// scal = {c_s, c_d} = {w_gat . att_src, w_gat . att_dst}
__global__ void prep_kernel(const float* __restrict__ w_gat, const float* __restrict__ att_src,
                            const float* __restrict__ att_dst, const float* __restrict__ b_gat,
                            const float* __restrict__ W_ih, const float* __restrict__ b_ih,
                            const float* __restrict__ b_hh,
                            float* __restrict__ W_eff, float* __restrict__ bias_eff,
                            float* __restrict__ scal) {
  int j = threadIdx.x;
  int blk = blockIdx.x;
  if (blk < NN) {
    float acc = 0.f;
#pragma unroll 8
    for (int f = 0; f < FF; ++f) acc = fmaf(w_gat[f], W_ih[(blk * FF + f) * G4 + j], acc);
    W_eff[blk * G4 + j] = acc;
  } else {
    float acc = b_ih[j] + b_hh[j];
    for (int f = 0; f < FF; ++f) {
      float bg = b_gat[f];
#pragma unroll 4
      for (int n = 0; n < NN; ++n) acc = fmaf(bg, W_ih[(n * FF + f) * G4 + j], acc);
    }
    bias_eff[j] = acc;
    if (j == 0) {
      float cs = 0.f, cd = 0.f;
      for (int f = 0; f < FF; ++f) {
        cs = fmaf(w_gat[f], att_src[f], cs);
        cd = fmaf(w_gat[f], att_dst[f], cd);
      }
      scal[0] = cs;
      scal[1] = cd;
    }
  }
}

// ---------------- GAT attention scalars: s[pos,n] ----------------
// block = 256 threads = 8 positions x 32 nodes
__global__ __launch_bounds__(256) void gat_kernel(const float* __restrict__ x_seq,
                                                  const int* __restrict__ ei,
                                                  const float* __restrict__ scal,
                                                  float* __restrict__ s_buf) {
  __shared__ int ep[ET];
  __shared__ float xs[8 * 33];  // +1 pad per row
  int tid = threadIdx.x;
  if (tid < ET) {
    int s, d;
    if (tid < 96) { s = ei[tid]; d = ei[96 + tid]; }
    else { s = tid - 96; d = tid - 96; }
    ep[tid] = s | (d << 16);
  }
  int p = tid >> 5, n = tid & 31;
  int pos = blockIdx.x * 8 + p;
  xs[p * 33 + n] = x_seq[pos * NN + n];  // coalesced: blockIdx*256 + tid
  __syncthreads();
  float cs = scal[0], cd = scal[1];
  int base = p * 33;
  // pass 1: segment max over edges with dst == n
  float m = -3.0e38f;
  for (int e = 0; e < ET; ++e) {
    int pe = ep[e];
    int se = pe & 0xffff, de = pe >> 16;
    float ev = cs * xs[base + se] + cd * xs[base + de];
    ev = ev > 0.f ? ev : 0.2f * ev;  // LeakyReLU(0.2)
    if (de == n) m = fmaxf(m, ev);
  }
  // pass 2: softmax-weighted sum of x[src]
  float z = 0.f, sa = 0.f;
  for (int e = 0; e < ET; ++e) {
    int pe = ep[e];
    int se = pe & 0xffff, de = pe >> 16;
    float xsv = xs[base + se];
    float ev = cs * xsv + cd * xs[base + de];
    ev = ev > 0.f ? ev : 0.2f * ev;
    float ex = __expf(ev - m);
    float exm = (de == n) ? ex : 0.f;
    z += exm;
    sa = fmaf(exm, xsv, sa);
  }
  s_buf[pos * NN + n] = sa * frcp(z);
}

// ---------------- xw[pos,j] = s[pos,:] @ W_eff[:,j] + bias_eff[j] ----------------
// block = 256 threads, each owns columns j=tid and j=tid+256; 32 positions per block
__global__ __launch_bounds__(256) void xw_kernel(const float* __restrict__ s_buf,
                                                 const float* __restrict__ W_eff,
                                                 const float* __restrict__ bias_eff,
                                                 float* __restrict__ xw) {
  __shared__ float sl[32 * NN];
  int tid = threadIdx.x;
  int posbase = blockIdx.x * 32;
#pragma unroll
  for (int r = 0; r < 4; ++r) sl[tid + r * 256] = s_buf[posbase * NN + tid + r * 256];
  float we0[NN], we1[NN];
#pragma unroll
  for (int nn = 0; nn < NN; ++nn) {
    we0[nn] = W_eff[nn * G4 + tid];
    we1[nn] = W_eff[nn * G4 + 256 + tid];
  }
  float b0 = bias_eff[tid], b1 = bias_eff[256 + tid];
  __syncthreads();
  for (int p = 0; p < 32; ++p) {
    const float4* sp = (const float4*)&sl[p * NN];
    float a0 = b0, a1 = b1;
#pragma unroll
    for (int q = 0; q < 8; ++q) {
      float4 sv = sp[q];
      a0 = fmaf(sv.x, we0[4 * q], a0);
      a0 = fmaf(sv.y, we0[4 * q + 1], a0);
      a0 = fmaf(sv.z, we0[4 * q + 2], a0);
      a0 = fmaf(sv.w, we0[4 * q + 3], a0);
      a1 = fmaf(sv.x, we1[4 * q], a1);
      a1 = fmaf(sv.y, we1[4 * q + 1], a1);
      a1 = fmaf(sv.z, we1[4 * q + 2], a1);
      a1 = fmaf(sv.w, we1[4 * q + 3], a1);
    }
    xw[(posbase + p) * G4 + tid] = a0;
    xw[(posbase + p) * G4 + 256 + tid] = a1;
  }
}

// ---------------- LSTM scan: one block per batch, thread j owns gate j ----------------
__global__ __launch_bounds__(512, 2) void lstm_kernel(const float* __restrict__ xw,
                                                      const float* __restrict__ W_hh,
                                                      const float* __restrict__ W_fc,
                                                      const float* __restrict__ b_fc,
                                                      float* __restrict__ out) {
  __shared__ float h_sh[HH];
  __shared__ float act[G4];
  int b = blockIdx.x, j = threadIdx.x;
  float w[HH];  // column j of W_hh, held in VGPRs
#pragma unroll
  for (int k = 0; k < HH; ++k) w[k] = W_hh[k * G4 + j];
  float c = 0.f;  // cell state, valid for j < HH
  if (j < HH) h_sh[j] = 0.f;
  bool is_g = (j >> 7) == 2;  // gate order i,f,g,o: g slice gets tanh
  const float* xwb = xw + (size_t)b * TT * G4;
  __syncthreads();
  for (int t = 0; t < TT; ++t) {
    float xv = xwb[t * G4 + j];  // issued early, consumed after the dot
    float acc0 = 0.f, acc1 = 0.f;  // two chains to break FMA latency
    const float4* hp = (const float4*)h_sh;
#pragma unroll
    for (int q = 0; q < HH / 4; q += 2) {
      float4 h0 = hp[q];
      float4 h1 = hp[q + 1];
      acc0 = fmaf(h0.x, w[4 * q], acc0);
      acc0 = fmaf(h0.y, w[4 * q + 1], acc0);
      acc0 = fmaf(h0.z, w[4 * q + 2], acc0);
      acc0 = fmaf(h0.w, w[4 * q + 3], acc0);
      acc1 = fmaf(h1.x, w[4 * q + 4], acc1);
      acc1 = fmaf(h1.y, w[4 * q + 5], acc1);
      acc1 = fmaf(h1.z, w[4 * q + 6], acc1);
      acc1 = fmaf(h1.w, w[4 * q + 7], acc1);
    }
    float acc = acc0 + acc1 + xv;
    float a = is_g ? tanh_fast(acc) : sigm(acc);
    act[j] = a;
    __syncthreads();  // all h_sh reads done + act visible
    if (j < HH) {
      float ig = act[j], fg = act[HH + j], gg = act[2 * HH + j], og = act[3 * HH + j];
      c = fmaf(fg, c, ig * gg);
      h_sh[j] = og * tanh_fast(c);
    }
    __syncthreads();  // h_sh ready for next step
  }
  // classifier: out[b, cls] = h_T . W_fc[:, cls] + b_fc[cls]
  if (j < 4) {
    float acc = b_fc[j];
#pragma unroll 8
    for (int k = 0; k < HH; ++k) acc = fmaf(h_sh[k], W_fc[k * 4 + j], acc);
    out[b * 4 + j] = acc;
  }
}

extern "C" void kernel_launch(void* const* d_in, const int* in_sizes, int n_in,
                              void* d_out, int out_size, void* d_ws, size_t ws_size,
                              hipStream_t stream) {
  const float* x_seq   = (const float*)d_in[0];
  const int*   ei      = (const int*)d_in[1];
  const float* w_gat   = (const float*)d_in[2];
  const float* att_src = (const float*)d_in[3];
  const float* att_dst = (const float*)d_in[4];
  const float* b_gat   = (const float*)d_in[5];
  const float* W_ih    = (const float*)d_in[6];
  const float* W_hh    = (const float*)d_in[7];
  const float* b_ih    = (const float*)d_in[8];
  const float* b_hh    = (const float*)d_in[9];
  const float* W_fc    = (const float*)d_in[10];
  const float* b_fc    = (const float*)d_in[11];

  float* ws = (float*)d_ws;
  float* s_buf    = ws;                          // 16384*32   = 524288 f
  float* xw       = s_buf + (size_t)NPOS * NN;   // 16384*512  = 8388608 f
  float* W_eff    = xw + (size_t)NPOS * G4;      // 32*512     = 16384 f
  float* bias_eff = W_eff + NN * G4;             // 512 f
  float* scal     = bias_eff + G4;               // 2 f   (total ~35.7 MB)

  prep_kernel<<<NN + 1, G4, 0, stream>>>(w_gat, att_src, att_dst, b_gat, W_ih, b_ih, b_hh,
                                         W_eff, bias_eff, scal);
  gat_kernel<<<NPOS / 8, 256, 0, stream>>>(x_seq, ei, scal, s_buf);
  xw_kernel<<<NPOS / 32, 256, 0, stream>>>(s_buf, W_eff, bias_eff, xw);
  lstm_kernel<<<BB, G4, 0, stream>>>(xw, W_hh, W_fc, b_fc, (float*)d_out);
}